// Round 13
// baseline (153.220 us; speedup 1.0000x reference)
//
#include <hip/hip_runtime.h>

// GRU with per-row sequence lengths. B=4096, T=200, I=64, H=128 (hardcoded).
// Output[b] = h after seq_lengths[b] steps from h0=0.
//
// Round-13 = r12 (143us) + critical-path reorder inside the step:
//  - ar chain completes by MFMA 4, az by MFMA 8; their 8 exp2 issue
//    immediately, then anh chain (4 MFMA) + x-part (6 MFMA) execute UNDER
//    the trans latency. Gate tail shrinks to the n-chain only.
//  - everything else identical to r12: 256 blocks x 512 thr, 16 rows,
//    8 waves x 16 cols, C^T layout (lane owns one batch row x 4 contiguous
//    h-cols -> b64 h-write, dwordx4 store), x LDS ring + mod-7 stagger
//    (mod-8 would race the chunk-boundary x(t+1) read), exp2-prescale +
//    sign-fold, parity ping-pong x-accumulators, frozen-h, __syncthreads.

#define I_DIM 64
#define H_DIM 128
#define CH 8     // x-chunk steps
#define HP 136   // h-tile row stride in halves (128 + 8 pad)
#define XP 72    // x-ring row stride in halves (64 + 8 pad)
#define LOG2E 1.44269504088896f

typedef _Float16 h8 __attribute__((ext_vector_type(8)));
typedef _Float16 h4 __attribute__((ext_vector_type(4)));
typedef float f4 __attribute__((ext_vector_type(4)));

__global__ __launch_bounds__(512, 2)
void gru_seq_kernel(const float* __restrict__ input,
                    const int* __restrict__ seq_lengths,
                    const float* __restrict__ W_ih,
                    const float* __restrict__ W_hh,
                    const float* __restrict__ b_ih,
                    const float* __restrict__ b_hh,
                    float* __restrict__ out,
                    int B, int T) {
    __shared__ __align__(16) _Float16 h_lds[2][16][HP];          // double-buffered h
    __shared__ __align__(16) _Float16 x_lds[2][CH][16][XP];      // x ring (2 chunks)

    const int tid  = threadIdx.x;
    const int lane = tid & 63;
    const int w    = tid >> 6;     // wave 0..7
    const int base = blockIdx.x * 16;
    const int boff = blockIdx.x % 7;   // stage-phase stagger (0..6; 7 would race)

    const int lrow  = lane & 15;   // batch row owned by this lane (C col)
    const int kgrp  = lane >> 4;   // 0..3
    const int kgrp8 = kgrp * 8;
    const int kgrp4 = kgrp * 4;
    const int cb    = w * 16 + kgrp4;   // first of this lane's 4 h-cols

    // ---- sequence lengths ----
    const int gb = base + lrow;
    const int L = (gb < B) ? seq_lengths[gb] : 0;   // per-lane scalar
    int Lmax = 0;
    for (int i = 0; i < 16; ++i) {
        int gr = base + i;
        int Li = (gr < B) ? seq_lengths[gr] : 0;
        Lmax = max(Lmax, Li);
    }
    if (Lmax > T) Lmax = T;

    // ---- bias vectors (element q -> h-col cb+q), prescaled + sign-folded ----
    const f4 brv  = (*(const f4*)(b_ih + cb) + *(const f4*)(b_hh + cb)) * (-LOG2E);
    const f4 bzv  = (*(const f4*)(b_ih + H_DIM + cb) + *(const f4*)(b_hh + H_DIM + cb)) * (-LOG2E);
    const f4 bnxv = (*(const f4*)(b_ih + 2 * H_DIM + cb)) * (2.f * LOG2E);
    const f4 bnhv = (*(const f4*)(b_hh + 2 * H_DIM + cb)) * (2.f * LOG2E);

    // ---- resident weight A-fragments (18 x h8 = 72 VGPR), prescaled ----
    h8 aw[18];
    {
        const int jrow = w * 16 + lrow;
#pragma unroll
        for (int gate = 0; gate < 3; ++gate) {
            const float gs = (gate == 2) ? (2.f * LOG2E) : (-LOG2E);
            const int j = gate * H_DIM + jrow;
#pragma unroll
            for (int kt = 0; kt < 6; ++kt) {
                const int kb = kt * 32 + kgrp8;
                const float* src = (kt < 4) ? (W_hh + j * H_DIM + kb)
                                            : (W_ih + j * I_DIM + (kb - H_DIM));
                f4 f0 = *(const f4*)(src);
                f4 f1 = *(const f4*)(src + 4);
                h8 v;
                v[0] = (_Float16)(f0[0] * gs); v[1] = (_Float16)(f0[1] * gs);
                v[2] = (_Float16)(f0[2] * gs); v[3] = (_Float16)(f0[3] * gs);
                v[4] = (_Float16)(f1[0] * gs); v[5] = (_Float16)(f1[1] * gs);
                v[6] = (_Float16)(f1[2] * gs); v[7] = (_Float16)(f1[3] * gs);
                aw[gate * 6 + kt] = v;
            }
        }
    }

    // ---- zero h buffer 0 (h(0) = 0) ----
    {
        int idx = tid * 4;             // 2048 halves / 512 threads
        int r = idx >> 7, cc = idx & 127;
        *(h4*)&h_lds[0][r][cc] = h4{0, 0, 0, 0};
    }

    // ---- x staging geometry: 32 thr/row; thread covers 4 steps ----
    const int srow = tid >> 5;                    // 0..15
    const int si0  = (tid & 31) >> 4;             // 0..1
    const int icol = (tid & 15) * 4;              // 0,4,..,60
    const int gxr  = base + srow;
    const float* xsrc = input + (size_t)gxr * T * I_DIM;
    const bool xok = (gxr < B);

    // prologue: stage chunk 0 (steps 0..7) into slot 0
    if (Lmax > 0) {
        f4 xv[4];
#pragma unroll
        for (int j = 0; j < 4; ++j) {
            int s = si0 + 2 * j;
            xv[j] = f4{0.f, 0.f, 0.f, 0.f};
            if (xok && s < T) xv[j] = *(const f4*)(xsrc + (size_t)s * I_DIM + icol);
        }
#pragma unroll
        for (int j = 0; j < 4; ++j) {
            int s = si0 + 2 * j;
            h4 hv;
            hv[0] = (_Float16)xv[j][0]; hv[1] = (_Float16)xv[j][1];
            hv[2] = (_Float16)xv[j][2]; hv[3] = (_Float16)xv[j][3];
            *(h4*)&x_lds[0][s][srow][icol] = hv;
        }
    }
    __syncthreads();

    // ---- x-part accumulators (gates^T layout), parity ping-pong ----
    f4 xar[2], xaz[2], xan[2];
    xar[0] = brv;
    xaz[0] = bzv;
    xan[0] = bnxv;
    if (Lmax > 0) {
        h8 xg0 = *(const h8*)&x_lds[0][0][lrow][kgrp8];
        h8 xg1 = *(const h8*)&x_lds[0][0][lrow][32 + kgrp8];
        xar[0] = __builtin_amdgcn_mfma_f32_16x16x32_f16(aw[4],  xg0, xar[0], 0, 0, 0);
        xaz[0] = __builtin_amdgcn_mfma_f32_16x16x32_f16(aw[10], xg0, xaz[0], 0, 0, 0);
        xan[0] = __builtin_amdgcn_mfma_f32_16x16x32_f16(aw[16], xg0, xan[0], 0, 0, 0);
        xar[0] = __builtin_amdgcn_mfma_f32_16x16x32_f16(aw[5],  xg1, xar[0], 0, 0, 0);
        xaz[0] = __builtin_amdgcn_mfma_f32_16x16x32_f16(aw[11], xg1, xaz[0], 0, 0, 0);
        xan[0] = __builtin_amdgcn_mfma_f32_16x16x32_f16(aw[17], xg1, xan[0], 0, 0, 0);
    }

    float hreg[4] = {0.f, 0.f, 0.f, 0.f};

#define STEP(P, TC) do {                                                              \
        const int t_ = (TC);                                                          \
        /* stage next-chunk loads at this block's stagger step */                     \
        f4 xv0, xv1, xv2, xv3;                                                        \
        const bool do_stage = ((t_ & 7) == boff) && (((t_ >> 3) + 1) * CH < Lmax);    \
        if (do_stage) {                                                               \
            const int t0 = ((t_ >> 3) + 1) * CH;                                      \
            xv0 = xv1 = xv2 = xv3 = f4{0.f, 0.f, 0.f, 0.f};                           \
            if (xok) {                                                                \
                int s0 = t0 + si0;                                                    \
                if (s0     < T) xv0 = *(const f4*)(xsrc + (size_t)(s0    ) * I_DIM + icol); \
                if (s0 + 2 < T) xv1 = *(const f4*)(xsrc + (size_t)(s0 + 2) * I_DIM + icol); \
                if (s0 + 4 < T) xv2 = *(const f4*)(xsrc + (size_t)(s0 + 4) * I_DIM + icol); \
                if (s0 + 6 < T) xv3 = *(const f4*)(xsrc + (size_t)(s0 + 6) * I_DIM + icol); \
            }                                                                         \
        }                                                                             \
        /* h B-frags */                                                               \
        h8 hb0 = *(const h8*)&h_lds[P][lrow][0 * 32 + kgrp8];                         \
        h8 hb1 = *(const h8*)&h_lds[P][lrow][1 * 32 + kgrp8];                         \
        h8 hb2 = *(const h8*)&h_lds[P][lrow][2 * 32 + kgrp8];                         \
        h8 hb3 = *(const h8*)&h_lds[P][lrow][3 * 32 + kgrp8];                         \
        /* x B-frags for step t+1 */                                                  \
        const int sl_ = ((t_ + 1) >> 3) & 1, ss_ = (t_ + 1) & 7;                      \
        h8 xg0 = *(const h8*)&x_lds[sl_][ss_][lrow][kgrp8];                           \
        h8 xg1 = *(const h8*)&x_lds[sl_][ss_][lrow][32 + kgrp8];                      \
        f4 ar  = xar[P];                                                              \
        f4 az  = xaz[P];                                                              \
        f4 axn = xan[P];                                                              \
        f4 anh = bnhv;                                                                \
        __builtin_amdgcn_s_setprio(1);                                                \
        /* ar chain first (done at MFMA 4) */                                         \
        ar  = __builtin_amdgcn_mfma_f32_16x16x32_f16(aw[0],  hb0, ar,  0, 0, 0);      \
        ar  = __builtin_amdgcn_mfma_f32_16x16x32_f16(aw[1],  hb1, ar,  0, 0, 0);      \
        ar  = __builtin_amdgcn_mfma_f32_16x16x32_f16(aw[2],  hb2, ar,  0, 0, 0);      \
        ar  = __builtin_amdgcn_mfma_f32_16x16x32_f16(aw[3],  hb3, ar,  0, 0, 0);      \
        /* az chain (done at MFMA 8) */                                               \
        az  = __builtin_amdgcn_mfma_f32_16x16x32_f16(aw[6],  hb0, az,  0, 0, 0);      \
        az  = __builtin_amdgcn_mfma_f32_16x16x32_f16(aw[7],  hb1, az,  0, 0, 0);      \
        az  = __builtin_amdgcn_mfma_f32_16x16x32_f16(aw[8],  hb2, az,  0, 0, 0);      \
        az  = __builtin_amdgcn_mfma_f32_16x16x32_f16(aw[9],  hb3, az,  0, 0, 0);      \
        /* r,z exponentials issue NOW; anh + x-part MFMAs run under them */           \
        float er0 = __builtin_amdgcn_exp2f(ar[0]);                                    \
        float er1 = __builtin_amdgcn_exp2f(ar[1]);                                    \
        float er2 = __builtin_amdgcn_exp2f(ar[2]);                                    \
        float er3 = __builtin_amdgcn_exp2f(ar[3]);                                    \
        float ez0 = __builtin_amdgcn_exp2f(az[0]);                                    \
        float ez1 = __builtin_amdgcn_exp2f(az[1]);                                    \
        float ez2 = __builtin_amdgcn_exp2f(az[2]);                                    \
        float ez3 = __builtin_amdgcn_exp2f(az[3]);                                    \
        /* anh chain */                                                               \
        anh = __builtin_amdgcn_mfma_f32_16x16x32_f16(aw[12], hb0, anh, 0, 0, 0);      \
        anh = __builtin_amdgcn_mfma_f32_16x16x32_f16(aw[13], hb1, anh, 0, 0, 0);      \
        anh = __builtin_amdgcn_mfma_f32_16x16x32_f16(aw[14], hb2, anh, 0, 0, 0);      \
        anh = __builtin_amdgcn_mfma_f32_16x16x32_f16(aw[15], hb3, anh, 0, 0, 0);      \
        /* x-part for step t+1 (independent) */                                       \
        if (t_ + 1 < Lmax) {                                                          \
            f4 a0 = brv;                                                              \
            f4 a1 = bzv;                                                              \
            f4 a2 = bnxv;                                                             \
            a0 = __builtin_amdgcn_mfma_f32_16x16x32_f16(aw[4],  xg0, a0, 0, 0, 0);    \
            a1 = __builtin_amdgcn_mfma_f32_16x16x32_f16(aw[10], xg0, a1, 0, 0, 0);    \
            a2 = __builtin_amdgcn_mfma_f32_16x16x32_f16(aw[16], xg0, a2, 0, 0, 0);    \
            a0 = __builtin_amdgcn_mfma_f32_16x16x32_f16(aw[5],  xg1, a0, 0, 0, 0);    \
            a1 = __builtin_amdgcn_mfma_f32_16x16x32_f16(aw[11], xg1, a1, 0, 0, 0);    \
            a2 = __builtin_amdgcn_mfma_f32_16x16x32_f16(aw[17], xg1, a2, 0, 0, 0);    \
            xar[(P) ^ 1] = a0; xaz[(P) ^ 1] = a1; xan[(P) ^ 1] = a2;                  \
        }                                                                             \
        __builtin_amdgcn_s_setprio(0);                                                \
        /* gate tail: r,z finish with one rcp each; n-chain is the only serial */     \
        const bool upd_ = (t_ < L);                                                   \
        float rr[4], zz[4];                                                           \
        rr[0] = __builtin_amdgcn_rcpf(1.0f + er0);                                    \
        rr[1] = __builtin_amdgcn_rcpf(1.0f + er1);                                    \
        rr[2] = __builtin_amdgcn_rcpf(1.0f + er2);                                    \
        rr[3] = __builtin_amdgcn_rcpf(1.0f + er3);                                    \
        zz[0] = __builtin_amdgcn_rcpf(1.0f + ez0);                                    \
        zz[1] = __builtin_amdgcn_rcpf(1.0f + ez1);                                    \
        zz[2] = __builtin_amdgcn_rcpf(1.0f + ez2);                                    \
        zz[3] = __builtin_amdgcn_rcpf(1.0f + ez3);                                    \
        _Pragma("unroll")                                                             \
        for (int q = 0; q < 4; ++q) {                                                 \
            float en   = __builtin_amdgcn_exp2f(axn[q] + rr[q] * anh[q]);             \
            float n    = 1.0f - 2.0f * __builtin_amdgcn_rcpf(en + 1.0f);              \
            float hnew = n + zz[q] * (hreg[q] - n);                                   \
            hreg[q] = upd_ ? hnew : hreg[q];                                          \
        }                                                                             \
        { /* ONE b64 h-write: 4 contiguous halves at [lrow][cb] */                    \
            h4 hv;                                                                    \
            hv[0] = (_Float16)hreg[0]; hv[1] = (_Float16)hreg[1];                     \
            hv[2] = (_Float16)hreg[2]; hv[3] = (_Float16)hreg[3];                     \
            *(h4*)&h_lds[(P) ^ 1][lrow][cb] = hv;                                     \
        }                                                                             \
        /* write staged x-chunk */                                                    \
        if (do_stage) {                                                               \
            const int ws_ = ((t_ >> 3) + 1) & 1;                                      \
            h4 hv;                                                                    \
            hv[0] = (_Float16)xv0[0]; hv[1] = (_Float16)xv0[1];                       \
            hv[2] = (_Float16)xv0[2]; hv[3] = (_Float16)xv0[3];                       \
            *(h4*)&x_lds[ws_][si0][srow][icol] = hv;                                  \
            hv[0] = (_Float16)xv1[0]; hv[1] = (_Float16)xv1[1];                       \
            hv[2] = (_Float16)xv1[2]; hv[3] = (_Float16)xv1[3];                       \
            *(h4*)&x_lds[ws_][si0 + 2][srow][icol] = hv;                              \
            hv[0] = (_Float16)xv2[0]; hv[1] = (_Float16)xv2[1];                       \
            hv[2] = (_Float16)xv2[2]; hv[3] = (_Float16)xv2[3];                       \
            *(h4*)&x_lds[ws_][si0 + 4][srow][icol] = hv;                              \
            hv[0] = (_Float16)xv3[0]; hv[1] = (_Float16)xv3[1];                       \
            hv[2] = (_Float16)xv3[2]; hv[3] = (_Float16)xv3[3];                       \
            *(h4*)&x_lds[ws_][si0 + 6][srow][icol] = hv;                              \
        }                                                                             \
        __syncthreads();                                                              \
    } while (0)

    int t = 0;
    for (; t + 1 < Lmax; t += 2) {
        STEP(0, t);
        STEP(1, t + 1);
    }
    if (t < Lmax) STEP(0, t);

#undef STEP

    // ---- store h (== hn via frozen-h): one dwordx4 per lane ----
    if (gb < B) {
        f4 o;
        o[0] = hreg[0]; o[1] = hreg[1]; o[2] = hreg[2]; o[3] = hreg[3];
        *(f4*)(out + (size_t)gb * H_DIM + cb) = o;
    }
}

extern "C" void kernel_launch(void* const* d_in, const int* in_sizes, int n_in,
                              void* d_out, int out_size, void* d_ws, size_t ws_size,
                              hipStream_t stream) {
    const float* input = (const float*)d_in[0];
    const int*   seq   = (const int*)d_in[1];
    const float* W_ih  = (const float*)d_in[2];
    const float* W_hh  = (const float*)d_in[3];
    const float* b_ih  = (const float*)d_in[4];
    const float* b_hh  = (const float*)d_in[5];
    float* out = (float*)d_out;

    const int B = in_sizes[1];
    const int T = in_sizes[0] / (B * I_DIM);

    const int grid = (B + 15) / 16;
    gru_seq_kernel<<<grid, 512, 0, stream>>>(input, seq, W_ih, W_hh, b_ih, b_hh, out, B, T);
}

// Round 14
// 142.951 us; speedup vs baseline: 1.0718x; 1.0718x over previous
//
#include <hip/hip_runtime.h>

// GRU with per-row sequence lengths. B=4096, T=200, I=64, H=128 (hardcoded).
// Output[b] = h after seq_lengths[b] steps from h0=0.
//
// Round-14 = exact r12 restore (measured optimum, 143us). r13's manual
// chain-serialized MFMA order regressed (dependent back-to-back MFMAs expose
// full MFMA latency; r12's round-robin ar/az/anh interleave is optimal and
// the compiler schedules trans under it). Structure summary:
//  - 256 blocks x 512 thr (8 waves, 2/SIMD), 16 real rows/block.
//  - C^T MFMA layout: gates^T = Wcat . [h|x]^T; lane owns one batch row x
//    4 contiguous h-cols -> ONE b64 h-write, scalar L check, dwordx4 store.
//  - aw[18] f16 weight A-frags resident (72 VGPR), exp2-prescaled with
//    sign-fold (-log2e for r/z, +2log2e for n) -> raw v_exp2/v_rcp gates.
//  - x staged in 8-step LDS ring, mod-7 stagger; x-part MFMAs pipelined
//    1 step ahead with parity ping-pong accumulators.
//  - frozen-h (h stops updating at t>=L) -> output == hreg, no hnreg.
//  - __syncthreads per step (raw barrier raced in r3); setprio around MFMA.

#define I_DIM 64
#define H_DIM 128
#define CH 8     // x-chunk steps
#define HP 136   // h-tile row stride in halves (128 + 8 pad)
#define XP 72    // x-ring row stride in halves (64 + 8 pad)
#define LOG2E 1.44269504088896f

typedef _Float16 h8 __attribute__((ext_vector_type(8)));
typedef _Float16 h4 __attribute__((ext_vector_type(4)));
typedef float f4 __attribute__((ext_vector_type(4)));

__device__ __forceinline__ float sig2n(float an) {  // an = -log2e * preact
    return __builtin_amdgcn_rcpf(1.0f + __builtin_amdgcn_exp2f(an));
}
__device__ __forceinline__ float tanh2(float ap) {  // ap = 2*log2e * preact
    return 1.0f - 2.0f * __builtin_amdgcn_rcpf(__builtin_amdgcn_exp2f(ap) + 1.0f);
}

__global__ __launch_bounds__(512, 2)
void gru_seq_kernel(const float* __restrict__ input,
                    const int* __restrict__ seq_lengths,
                    const float* __restrict__ W_ih,
                    const float* __restrict__ W_hh,
                    const float* __restrict__ b_ih,
                    const float* __restrict__ b_hh,
                    float* __restrict__ out,
                    int B, int T) {
    __shared__ __align__(16) _Float16 h_lds[2][16][HP];          // double-buffered h
    __shared__ __align__(16) _Float16 x_lds[2][CH][16][XP];      // x ring (2 chunks)

    const int tid  = threadIdx.x;
    const int lane = tid & 63;
    const int w    = tid >> 6;     // wave 0..7
    const int base = blockIdx.x * 16;
    const int boff = blockIdx.x % 7;   // stage-phase stagger (0..6)

    const int lrow  = lane & 15;   // batch row owned by this lane (C col)
    const int kgrp  = lane >> 4;   // 0..3
    const int kgrp8 = kgrp * 8;
    const int kgrp4 = kgrp * 4;
    const int cb    = w * 16 + kgrp4;   // first of this lane's 4 h-cols

    // ---- sequence lengths ----
    const int gb = base + lrow;
    const int L = (gb < B) ? seq_lengths[gb] : 0;   // per-lane scalar
    int Lmax = 0;
    for (int i = 0; i < 16; ++i) {
        int gr = base + i;
        int Li = (gr < B) ? seq_lengths[gr] : 0;
        Lmax = max(Lmax, Li);
    }
    if (Lmax > T) Lmax = T;

    // ---- bias vectors (element q -> h-col cb+q), prescaled + sign-folded ----
    const f4 brv  = (*(const f4*)(b_ih + cb) + *(const f4*)(b_hh + cb)) * (-LOG2E);
    const f4 bzv  = (*(const f4*)(b_ih + H_DIM + cb) + *(const f4*)(b_hh + H_DIM + cb)) * (-LOG2E);
    const f4 bnxv = (*(const f4*)(b_ih + 2 * H_DIM + cb)) * (2.f * LOG2E);
    const f4 bnhv = (*(const f4*)(b_hh + 2 * H_DIM + cb)) * (2.f * LOG2E);

    // ---- resident weight A-fragments (18 x h8 = 72 VGPR), prescaled ----
    h8 aw[18];
    {
        const int jrow = w * 16 + lrow;
#pragma unroll
        for (int gate = 0; gate < 3; ++gate) {
            const float gs = (gate == 2) ? (2.f * LOG2E) : (-LOG2E);
            const int j = gate * H_DIM + jrow;
#pragma unroll
            for (int kt = 0; kt < 6; ++kt) {
                const int kb = kt * 32 + kgrp8;
                const float* src = (kt < 4) ? (W_hh + j * H_DIM + kb)
                                            : (W_ih + j * I_DIM + (kb - H_DIM));
                f4 f0 = *(const f4*)(src);
                f4 f1 = *(const f4*)(src + 4);
                h8 v;
                v[0] = (_Float16)(f0[0] * gs); v[1] = (_Float16)(f0[1] * gs);
                v[2] = (_Float16)(f0[2] * gs); v[3] = (_Float16)(f0[3] * gs);
                v[4] = (_Float16)(f1[0] * gs); v[5] = (_Float16)(f1[1] * gs);
                v[6] = (_Float16)(f1[2] * gs); v[7] = (_Float16)(f1[3] * gs);
                aw[gate * 6 + kt] = v;
            }
        }
    }

    // ---- zero h buffer 0 (h(0) = 0) ----
    {
        int idx = tid * 4;             // 2048 halves / 512 threads
        int r = idx >> 7, cc = idx & 127;
        *(h4*)&h_lds[0][r][cc] = h4{0, 0, 0, 0};
    }

    // ---- x staging geometry: 32 thr/row; thread covers 4 steps ----
    const int srow = tid >> 5;                    // 0..15
    const int si0  = (tid & 31) >> 4;             // 0..1
    const int icol = (tid & 15) * 4;              // 0,4,..,60
    const int gxr  = base + srow;
    const float* xsrc = input + (size_t)gxr * T * I_DIM;
    const bool xok = (gxr < B);

    // prologue: stage chunk 0 (steps 0..7) into slot 0
    if (Lmax > 0) {
        f4 xv[4];
#pragma unroll
        for (int j = 0; j < 4; ++j) {
            int s = si0 + 2 * j;
            xv[j] = f4{0.f, 0.f, 0.f, 0.f};
            if (xok && s < T) xv[j] = *(const f4*)(xsrc + (size_t)s * I_DIM + icol);
        }
#pragma unroll
        for (int j = 0; j < 4; ++j) {
            int s = si0 + 2 * j;
            h4 hv;
            hv[0] = (_Float16)xv[j][0]; hv[1] = (_Float16)xv[j][1];
            hv[2] = (_Float16)xv[j][2]; hv[3] = (_Float16)xv[j][3];
            *(h4*)&x_lds[0][s][srow][icol] = hv;
        }
    }
    __syncthreads();

    // ---- x-part accumulators (gates^T layout), parity ping-pong ----
    f4 xar[2], xaz[2], xan[2];
    xar[0] = brv;
    xaz[0] = bzv;
    xan[0] = bnxv;
    if (Lmax > 0) {
        h8 xg0 = *(const h8*)&x_lds[0][0][lrow][kgrp8];
        h8 xg1 = *(const h8*)&x_lds[0][0][lrow][32 + kgrp8];
        xar[0] = __builtin_amdgcn_mfma_f32_16x16x32_f16(aw[4],  xg0, xar[0], 0, 0, 0);
        xaz[0] = __builtin_amdgcn_mfma_f32_16x16x32_f16(aw[10], xg0, xaz[0], 0, 0, 0);
        xan[0] = __builtin_amdgcn_mfma_f32_16x16x32_f16(aw[16], xg0, xan[0], 0, 0, 0);
        xar[0] = __builtin_amdgcn_mfma_f32_16x16x32_f16(aw[5],  xg1, xar[0], 0, 0, 0);
        xaz[0] = __builtin_amdgcn_mfma_f32_16x16x32_f16(aw[11], xg1, xaz[0], 0, 0, 0);
        xan[0] = __builtin_amdgcn_mfma_f32_16x16x32_f16(aw[17], xg1, xan[0], 0, 0, 0);
    }

    float hreg[4] = {0.f, 0.f, 0.f, 0.f};

#define STEP(P, TC) do {                                                              \
        const int t_ = (TC);                                                          \
        /* stage next-chunk loads at this block's stagger step */                     \
        f4 xv0, xv1, xv2, xv3;                                                        \
        const bool do_stage = ((t_ & 7) == boff) && (((t_ >> 3) + 1) * CH < Lmax);    \
        if (do_stage) {                                                               \
            const int t0 = ((t_ >> 3) + 1) * CH;                                      \
            xv0 = xv1 = xv2 = xv3 = f4{0.f, 0.f, 0.f, 0.f};                           \
            if (xok) {                                                                \
                int s0 = t0 + si0;                                                    \
                if (s0     < T) xv0 = *(const f4*)(xsrc + (size_t)(s0    ) * I_DIM + icol); \
                if (s0 + 2 < T) xv1 = *(const f4*)(xsrc + (size_t)(s0 + 2) * I_DIM + icol); \
                if (s0 + 4 < T) xv2 = *(const f4*)(xsrc + (size_t)(s0 + 4) * I_DIM + icol); \
                if (s0 + 6 < T) xv3 = *(const f4*)(xsrc + (size_t)(s0 + 6) * I_DIM + icol); \
            }                                                                         \
        }                                                                             \
        /* h B-frags: B[k][n]=h[n=lrow][k] */                                         \
        h8 hb0 = *(const h8*)&h_lds[P][lrow][0 * 32 + kgrp8];                         \
        h8 hb1 = *(const h8*)&h_lds[P][lrow][1 * 32 + kgrp8];                         \
        h8 hb2 = *(const h8*)&h_lds[P][lrow][2 * 32 + kgrp8];                         \
        h8 hb3 = *(const h8*)&h_lds[P][lrow][3 * 32 + kgrp8];                         \
        /* x B-frags for step t+1 */                                                  \
        const int sl_ = ((t_ + 1) >> 3) & 1, ss_ = (t_ + 1) & 7;                      \
        h8 xg0 = *(const h8*)&x_lds[sl_][ss_][lrow][kgrp8];                           \
        h8 xg1 = *(const h8*)&x_lds[sl_][ss_][lrow][32 + kgrp8];                      \
        f4 ar  = xar[P];                                                              \
        f4 az  = xaz[P];                                                              \
        f4 axn = xan[P];                                                              \
        f4 anh = bnhv;                                                                \
        __builtin_amdgcn_s_setprio(1);                                                \
        ar  = __builtin_amdgcn_mfma_f32_16x16x32_f16(aw[0],  hb0, ar,  0, 0, 0);      \
        az  = __builtin_amdgcn_mfma_f32_16x16x32_f16(aw[6],  hb0, az,  0, 0, 0);      \
        anh = __builtin_amdgcn_mfma_f32_16x16x32_f16(aw[12], hb0, anh, 0, 0, 0);      \
        ar  = __builtin_amdgcn_mfma_f32_16x16x32_f16(aw[1],  hb1, ar,  0, 0, 0);      \
        az  = __builtin_amdgcn_mfma_f32_16x16x32_f16(aw[7],  hb1, az,  0, 0, 0);      \
        anh = __builtin_amdgcn_mfma_f32_16x16x32_f16(aw[13], hb1, anh, 0, 0, 0);      \
        ar  = __builtin_amdgcn_mfma_f32_16x16x32_f16(aw[2],  hb2, ar,  0, 0, 0);      \
        az  = __builtin_amdgcn_mfma_f32_16x16x32_f16(aw[8],  hb2, az,  0, 0, 0);      \
        anh = __builtin_amdgcn_mfma_f32_16x16x32_f16(aw[14], hb2, anh, 0, 0, 0);      \
        ar  = __builtin_amdgcn_mfma_f32_16x16x32_f16(aw[3],  hb3, ar,  0, 0, 0);      \
        az  = __builtin_amdgcn_mfma_f32_16x16x32_f16(aw[9],  hb3, az,  0, 0, 0);      \
        anh = __builtin_amdgcn_mfma_f32_16x16x32_f16(aw[15], hb3, anh, 0, 0, 0);      \
        /* x-part for step t+1 (independent) */                                       \
        if (t_ + 1 < Lmax) {                                                          \
            f4 a0 = brv;                                                              \
            f4 a1 = bzv;                                                              \
            f4 a2 = bnxv;                                                             \
            a0 = __builtin_amdgcn_mfma_f32_16x16x32_f16(aw[4],  xg0, a0, 0, 0, 0);    \
            a1 = __builtin_amdgcn_mfma_f32_16x16x32_f16(aw[10], xg0, a1, 0, 0, 0);    \
            a2 = __builtin_amdgcn_mfma_f32_16x16x32_f16(aw[16], xg0, a2, 0, 0, 0);    \
            a0 = __builtin_amdgcn_mfma_f32_16x16x32_f16(aw[5],  xg1, a0, 0, 0, 0);    \
            a1 = __builtin_amdgcn_mfma_f32_16x16x32_f16(aw[11], xg1, a1, 0, 0, 0);    \
            a2 = __builtin_amdgcn_mfma_f32_16x16x32_f16(aw[17], xg1, a2, 0, 0, 0);    \
            xar[(P) ^ 1] = a0; xaz[(P) ^ 1] = a1; xan[(P) ^ 1] = a2;                  \
        }                                                                             \
        __builtin_amdgcn_s_setprio(0);                                                \
        /* gates: lane = batch row lrow, cols cb..cb+3; frozen-h at L */              \
        const bool upd_ = (t_ < L);                                                   \
        _Pragma("unroll")                                                             \
        for (int q = 0; q < 4; ++q) {                                                 \
            float r    = sig2n(ar[q]);                                                \
            float z    = sig2n(az[q]);                                                \
            float n    = tanh2(axn[q] + r * anh[q]);                                  \
            float hnew = n + z * (hreg[q] - n);                                       \
            hreg[q] = upd_ ? hnew : hreg[q];                                          \
        }                                                                             \
        { /* ONE b64 h-write: 4 contiguous halves at [lrow][cb] */                    \
            h4 hv;                                                                    \
            hv[0] = (_Float16)hreg[0]; hv[1] = (_Float16)hreg[1];                     \
            hv[2] = (_Float16)hreg[2]; hv[3] = (_Float16)hreg[3];                     \
            *(h4*)&h_lds[(P) ^ 1][lrow][cb] = hv;                                     \
        }                                                                             \
        /* write staged x-chunk */                                                    \
        if (do_stage) {                                                               \
            const int ws_ = ((t_ >> 3) + 1) & 1;                                      \
            h4 hv;                                                                    \
            hv[0] = (_Float16)xv0[0]; hv[1] = (_Float16)xv0[1];                       \
            hv[2] = (_Float16)xv0[2]; hv[3] = (_Float16)xv0[3];                       \
            *(h4*)&x_lds[ws_][si0][srow][icol] = hv;                                  \
            hv[0] = (_Float16)xv1[0]; hv[1] = (_Float16)xv1[1];                       \
            hv[2] = (_Float16)xv1[2]; hv[3] = (_Float16)xv1[3];                       \
            *(h4*)&x_lds[ws_][si0 + 2][srow][icol] = hv;                              \
            hv[0] = (_Float16)xv2[0]; hv[1] = (_Float16)xv2[1];                       \
            hv[2] = (_Float16)xv2[2]; hv[3] = (_Float16)xv2[3];                       \
            *(h4*)&x_lds[ws_][si0 + 4][srow][icol] = hv;                              \
            hv[0] = (_Float16)xv3[0]; hv[1] = (_Float16)xv3[1];                       \
            hv[2] = (_Float16)xv3[2]; hv[3] = (_Float16)xv3[3];                       \
            *(h4*)&x_lds[ws_][si0 + 6][srow][icol] = hv;                              \
        }                                                                             \
        __syncthreads();                                                              \
    } while (0)

    int t = 0;
    for (; t + 1 < Lmax; t += 2) {
        STEP(0, t);
        STEP(1, t + 1);
    }
    if (t < Lmax) STEP(0, t);

#undef STEP

    // ---- store h (== hn via frozen-h): one dwordx4 per lane ----
    if (gb < B) {
        f4 o;
        o[0] = hreg[0]; o[1] = hreg[1]; o[2] = hreg[2]; o[3] = hreg[3];
        *(f4*)(out + (size_t)gb * H_DIM + cb) = o;
    }
}

extern "C" void kernel_launch(void* const* d_in, const int* in_sizes, int n_in,
                              void* d_out, int out_size, void* d_ws, size_t ws_size,
                              hipStream_t stream) {
    const float* input = (const float*)d_in[0];
    const int*   seq   = (const int*)d_in[1];
    const float* W_ih  = (const float*)d_in[2];
    const float* W_hh  = (const float*)d_in[3];
    const float* b_ih  = (const float*)d_in[4];
    const float* b_hh  = (const float*)d_in[5];
    float* out = (float*)d_out;

    const int B = in_sizes[1];
    const int T = in_sizes[0] / (B * I_DIM);

    const int grid = (B + 15) / 16;
    gru_seq_kernel<<<grid, 512, 0, stream>>>(input, seq, W_ih, W_hh, b_ih, b_hh, out, B, T);
}